// Round 1
// baseline (488.752 us; speedup 1.0000x reference)
//
#include <hip/hip_runtime.h>

// Sizes fixed by the problem (asserted against in_sizes at launch).
constexpr int IN_FEAT = 256;
constexpr int HID     = 64;
constexpr int OUT     = 32;

// ---------------------------------------------------------------------------
// Kernel 1: fold the two linear layers.
//   W[k][c]  = sum_h fc1_w[h][k] * gcn_w[h][c]      (256 x 32)
//   bhw[c]   = sum_h fc1_b[h]    * gcn_w[h][c]      (32)
// ---------------------------------------------------------------------------
__global__ __launch_bounds__(256) void prep_W(
    const float* __restrict__ fc1_w,   // [HID][IN_FEAT]
    const float* __restrict__ fc1_b,   // [HID]
    const float* __restrict__ gcn_w,   // [HID][OUT]
    float* __restrict__ W,             // [IN_FEAT][OUT]
    float* __restrict__ bhw)           // [OUT]
{
    int idx = blockIdx.x * 256 + threadIdx.x;   // 0 .. 8191
    int k = idx >> 5;        // 0..255
    int c = idx & 31;        // 0..31
    float acc = 0.f;
#pragma unroll
    for (int h = 0; h < HID; ++h)
        acc += fc1_w[h * IN_FEAT + k] * gcn_w[h * OUT + c];
    W[k * OUT + c] = acc;

    if (idx < OUT) {
        float b = 0.f;
#pragma unroll
        for (int h = 0; h < HID; ++h)
            b += fc1_b[h] * gcn_w[h * OUT + idx];
        bhw[idx] = b;
    }
}

// ---------------------------------------------------------------------------
// Degree: init to 1 (self loop), count in-edges, then rsqrt in place.
// ---------------------------------------------------------------------------
__global__ __launch_bounds__(256) void deg_init(float* __restrict__ deg, int n)
{
    int i = blockIdx.x * 256 + threadIdx.x;
    if (i < n) deg[i] = 1.0f;
}

__global__ __launch_bounds__(256) void deg_count(
    const int* __restrict__ dst, float* __restrict__ deg, int E)
{
    int e = blockIdx.x * 256 + threadIdx.x;
    if (e < E) atomicAdd(&deg[dst[e]], 1.0f);
}

__global__ __launch_bounds__(256) void deg_rsqrt(float* __restrict__ deg, int n)
{
    int i = blockIdx.x * 256 + threadIdx.x;
    if (i < n) deg[i] = rsqrtf(deg[i]);   // deg >= 1 always (self loop)
}

// ---------------------------------------------------------------------------
// Kernel 2: hw = x @ W + bhw      [N,256]x[256,32]
// Epilogue:  out[i][c] = gcn_b[c] + dinv[i]^2 * hw[i][c]   (self-loop + bias)
// Block = 256 threads, 16 rows per block. W (32 KB) + x-tile (16 KB) in LDS.
// ---------------------------------------------------------------------------
__global__ __launch_bounds__(256) void gemm_hw(
    const float* __restrict__ x,      // [N][256]
    const float* __restrict__ W,      // [256][32]
    const float* __restrict__ bhw,    // [32]
    const float* __restrict__ dinv,   // [N]
    const float* __restrict__ gcn_b,  // [32]
    float* __restrict__ hw,           // [N][32]
    float* __restrict__ out,          // [N][32]
    int n)
{
    __shared__ float sW[IN_FEAT * OUT];       // 32 KB
    __shared__ float sx[16][IN_FEAT];         // 16 KB

    int t = threadIdx.x;

    // Load W: 8192 floats = 2048 float4, coalesced.
    for (int i = t; i < (IN_FEAT * OUT) / 4; i += 256)
        reinterpret_cast<float4*>(sW)[i] = reinterpret_cast<const float4*>(W)[i];

    // Load 16 rows of x: 1024 float4, coalesced (guard tail rows).
    int row0 = blockIdx.x * 16;
    for (int i = t; i < 1024; i += 256) {
        int r  = i >> 6;        // 64 float4 per row
        int k4 = i & 63;
        int row = row0 + r;
        float4 v = make_float4(0.f, 0.f, 0.f, 0.f);
        if (row < n) v = reinterpret_cast<const float4*>(x + (size_t)row * IN_FEAT)[k4];
        reinterpret_cast<float4*>(&sx[r][0])[k4] = v;
    }
    __syncthreads();

    int wave = t >> 6;        // 0..3
    int lane = t & 63;
    int half = lane >> 5;     // 0/1
    int c    = lane & 31;     // output feature

    // Each wave computes 4 rows (2 at a time: one per half-wave).
#pragma unroll
    for (int rr = 0; rr < 4; rr += 2) {
        int r = wave * 4 + rr + half;         // row within block, 0..15
        float acc = 0.f;
        const float4* xr = reinterpret_cast<const float4*>(&sx[r][0]);
#pragma unroll 8
        for (int k4 = 0; k4 < IN_FEAT / 4; ++k4) {
            float4 xv = xr[k4];
            int k = k4 * 4;
            acc += xv.x * sW[(k + 0) * OUT + c];
            acc += xv.y * sW[(k + 1) * OUT + c];
            acc += xv.z * sW[(k + 2) * OUT + c];
            acc += xv.w * sW[(k + 3) * OUT + c];
        }
        int row = row0 + r;
        if (row < n) {
            float hv = acc + bhw[c];
            hw[(size_t)row * OUT + c] = hv;
            float di = dinv[row];
            out[(size_t)row * OUT + c] = gcn_b[c] + di * di * hv;
        }
    }
}

// ---------------------------------------------------------------------------
// Kernel 3: edge scatter.  Half-wave (32 lanes) per edge, lane = feature.
//   out[d][c] += dinv[s]*dinv[d] * hw[s][c]
// ---------------------------------------------------------------------------
__global__ __launch_bounds__(256) void scatter_edges(
    const int* __restrict__ src,
    const int* __restrict__ dst,
    const float* __restrict__ dinv,
    const float* __restrict__ hw,
    float* __restrict__ out,
    int E)
{
    int t = blockIdx.x * 256 + threadIdx.x;
    int e = t >> 5;
    int c = t & 31;
    if (e >= E) return;
    int s = src[e];
    int d = dst[e];
    float w = dinv[s] * dinv[d];
    atomicAdd(&out[(size_t)d * OUT + c], w * hw[(size_t)s * OUT + c]);
}

// ---------------------------------------------------------------------------
extern "C" void kernel_launch(void* const* d_in, const int* in_sizes, int n_in,
                              void* d_out, int out_size, void* d_ws, size_t ws_size,
                              hipStream_t stream)
{
    const float* x      = (const float*)d_in[0];
    const int*   eidx   = (const int*)d_in[1];   // [2][E], int32 per harness
    const float* fc1_w  = (const float*)d_in[2];
    const float* fc1_b  = (const float*)d_in[3];
    const float* gcn_w  = (const float*)d_in[4];
    const float* gcn_b  = (const float*)d_in[5];
    float* out = (float*)d_out;

    int n = in_sizes[0] / IN_FEAT;
    int E = in_sizes[1] / 2;
    const int* src = eidx;
    const int* dst = eidx + E;

    // Workspace layout (floats):
    //   W    : [0, 8192)
    //   bhw  : [8192, 8224)
    //   dinv : [8224, 8224+n)
    //   hw   : aligned after dinv, n*32 floats
    float* ws   = (float*)d_ws;
    float* W    = ws;
    float* bhw  = ws + IN_FEAT * OUT;
    float* dinv = bhw + OUT;
    size_t hw_off = (size_t)(IN_FEAT * OUT + OUT + n + 31) & ~(size_t)31;
    float* hw   = ws + hw_off;

    dim3 blk(256);

    prep_W<<<dim3((IN_FEAT * OUT) / 256), blk, 0, stream>>>(fc1_w, fc1_b, gcn_w, W, bhw);
    deg_init<<<dim3((n + 255) / 256), blk, 0, stream>>>(dinv, n);
    deg_count<<<dim3((E + 255) / 256), blk, 0, stream>>>(dst, dinv, E);
    deg_rsqrt<<<dim3((n + 255) / 256), blk, 0, stream>>>(dinv, n);
    gemm_hw<<<dim3((n + 15) / 16), blk, 0, stream>>>(x, W, bhw, dinv, gcn_b, hw, out, n);

    long long total = (long long)E * 32;
    int nblk = (int)((total + 255) / 256);
    scatter_edges<<<dim3(nblk), blk, 0, stream>>>(src, dst, dinv, hw, out, E);
}

// Round 3
// 444.506 us; speedup vs baseline: 1.0995x; 1.0995x over previous
//
#include <hip/hip_runtime.h>

constexpr int IN_FEAT = 256;
constexpr int HID     = 64;
constexpr int OUT     = 32;

// ---------------------------------------------------------------------------
// Fold the two linears: W[k][c] = sum_h fc1_w[h][k]*gcn_w[h][c]; bhw = fc1_b@gcn_w
// ---------------------------------------------------------------------------
__global__ __launch_bounds__(256) void prep_W(
    const float* __restrict__ fc1_w,   // [HID][IN_FEAT]
    const float* __restrict__ fc1_b,   // [HID]
    const float* __restrict__ gcn_w,   // [HID][OUT]
    float* __restrict__ W,             // [IN_FEAT][OUT]
    float* __restrict__ bhw)           // [OUT]
{
    int idx = blockIdx.x * 256 + threadIdx.x;   // 0 .. 8191
    int k = idx >> 5;
    int c = idx & 31;
    float acc = 0.f;
#pragma unroll
    for (int h = 0; h < HID; ++h)
        acc += fc1_w[h * IN_FEAT + k] * gcn_w[h * OUT + c];
    W[k * OUT + c] = acc;

    if (idx < OUT) {
        float b = 0.f;
#pragma unroll
        for (int h = 0; h < HID; ++h)
            b += fc1_b[h] * gcn_w[h * OUT + idx];
        bhw[idx] = b;
    }
}

// ---------------------------------------------------------------------------
// Degree counting (int) + CSR build via counting sort.
// ---------------------------------------------------------------------------
__global__ __launch_bounds__(256) void zero_cnt(int* __restrict__ cnt, int n)
{
    int i = blockIdx.x * 256 + threadIdx.x;
    if (i < n) cnt[i] = 0;
}

__global__ __launch_bounds__(256) void count_deg(
    const int* __restrict__ dst, int* __restrict__ cnt, int E)
{
    int e = blockIdx.x * 256 + threadIdx.x;
    if (e < E) atomicAdd(&cnt[dst[e]], 1);
}

// scan stage 1: per-1024-element block sums
__global__ __launch_bounds__(256) void scan1(
    const int* __restrict__ cnt, int* __restrict__ bsum, int n)
{
    int t = threadIdx.x;
    int i = blockIdx.x * 1024 + t * 4;
    int s = 0;
    if (i + 3 < n) {
        int4 v = *reinterpret_cast<const int4*>(&cnt[i]);
        s = v.x + v.y + v.z + v.w;
    } else {
        for (int j = 0; j < 4; ++j) if (i + j < n) s += cnt[i + j];
    }
    for (int d = 32; d; d >>= 1) s += __shfl_down(s, d, 64);
    __shared__ int ws[4];
    if ((t & 63) == 0) ws[t >> 6] = s;
    __syncthreads();
    if (t == 0) bsum[blockIdx.x] = ws[0] + ws[1] + ws[2] + ws[3];
}

// scan stage 2: serial exclusive scan of block sums (nb ~ 98, trivial)
__global__ void scan2(int* __restrict__ bsum, int nb)
{
    if (threadIdx.x == 0 && blockIdx.x == 0) {
        int acc = 0;
        for (int i = 0; i < nb; ++i) { int v = bsum[i]; bsum[i] = acc; acc += v; }
    }
}

// scan stage 3: full exclusive offsets + cursor init + dinv = rsqrt(deg+1)
__global__ __launch_bounds__(256) void scan3(
    const int* __restrict__ cnt, const int* __restrict__ bsum,
    int* __restrict__ off, int* __restrict__ cur,
    float* __restrict__ dinv, int n)
{
    int t = threadIdx.x;
    int i = blockIdx.x * 1024 + t * 4;
    int c0 = 0, c1 = 0, c2 = 0, c3 = 0;
    if (i + 3 < n) {
        int4 v = *reinterpret_cast<const int4*>(&cnt[i]);
        c0 = v.x; c1 = v.y; c2 = v.z; c3 = v.w;
    } else {
        if (i     < n) c0 = cnt[i];
        if (i + 1 < n) c1 = cnt[i + 1];
        if (i + 2 < n) c2 = cnt[i + 2];
        if (i + 3 < n) c3 = cnt[i + 3];
    }
    int s = c0 + c1 + c2 + c3;
    int lane = t & 63;
    int incl = s;
    for (int d = 1; d < 64; d <<= 1) {
        int u = __shfl_up(incl, d, 64);
        if (lane >= d) incl += u;
    }
    __shared__ int wtot[4];
    if (lane == 63) wtot[t >> 6] = incl;
    __syncthreads();
    int w = t >> 6;
    int wbase = 0;
    for (int j = 0; j < 4; ++j) if (j < w) wbase += wtot[j];
    int ebase = bsum[blockIdx.x] + wbase + (incl - s);

    if (i     < n) { off[i]   = ebase;            cur[i]   = 0; dinv[i]   = rsqrtf((float)(c0 + 1)); }
    if (i + 1 < n) { off[i+1] = ebase + c0;       cur[i+1] = 0; dinv[i+1] = rsqrtf((float)(c1 + 1)); }
    if (i + 2 < n) { off[i+2] = ebase + c0 + c1;  cur[i+2] = 0; dinv[i+2] = rsqrtf((float)(c2 + 1)); }
    if (i + 3 < n) { off[i+3] = ebase + c0+c1+c2; cur[i+3] = 0; dinv[i+3] = rsqrtf((float)(c3 + 1)); }
}

// permute edges into dst-grouped records {src, norm}
__global__ __launch_bounds__(256) void permute_edges(
    const int* __restrict__ src, const int* __restrict__ dst,
    const int* __restrict__ off, int* __restrict__ cur,
    const float* __restrict__ dinv, int2* __restrict__ edata, int E)
{
    int e = blockIdx.x * 256 + threadIdx.x;
    if (e >= E) return;
    int s = src[e];
    int d = dst[e];
    int pos = off[d] + atomicAdd(&cur[d], 1);
    float w = dinv[s] * dinv[d];
    edata[pos] = make_int2(s, __float_as_int(w));
}

// ---------------------------------------------------------------------------
// hw = x @ W + bhw.   32 rows/block, 4 rows/thread: one W read feeds 4 FMAs.
// ---------------------------------------------------------------------------
__global__ __launch_bounds__(256) void gemm_hw2(
    const float* __restrict__ x,      // [N][256]
    const float* __restrict__ W,      // [256][32]
    const float* __restrict__ bhw,    // [32]
    float* __restrict__ hw,           // [N][32]
    int n)
{
    __shared__ float sW[IN_FEAT * OUT];   // 32 KB, layout [k][c]
    __shared__ float sx[32][IN_FEAT];     // 32 KB

    int t = threadIdx.x;

    for (int i = t; i < (IN_FEAT * OUT) / 4; i += 256)
        reinterpret_cast<float4*>(sW)[i] = reinterpret_cast<const float4*>(W)[i];

    int row0 = blockIdx.x * 32;
    for (int i = t; i < (32 * IN_FEAT) / 4; i += 256) {
        int r  = i >> 6;
        int k4 = i & 63;
        int row = row0 + r;
        float4 v = make_float4(0.f, 0.f, 0.f, 0.f);
        if (row < n) v = reinterpret_cast<const float4*>(x + (size_t)row * IN_FEAT)[k4];
        reinterpret_cast<float4*>(&sx[r][0])[k4] = v;
    }
    __syncthreads();

    int c = t & 31;          // output feature
    int g = t >> 5;          // row group 0..7
    const float4* x0 = reinterpret_cast<const float4*>(&sx[g * 4 + 0][0]);
    const float4* x1 = reinterpret_cast<const float4*>(&sx[g * 4 + 1][0]);
    const float4* x2 = reinterpret_cast<const float4*>(&sx[g * 4 + 2][0]);
    const float4* x3 = reinterpret_cast<const float4*>(&sx[g * 4 + 3][0]);

    float a0 = 0.f, a1 = 0.f, a2 = 0.f, a3 = 0.f;
#pragma unroll 8
    for (int k4 = 0; k4 < IN_FEAT / 4; ++k4) {
        int k = k4 * 4;
        float w0 = sW[(k + 0) * OUT + c];    // conflict-free b32 (bank = c)
        float w1 = sW[(k + 1) * OUT + c];
        float w2 = sW[(k + 2) * OUT + c];
        float w3 = sW[(k + 3) * OUT + c];
        float4 v0 = x0[k4];                  // broadcast b128
        float4 v1 = x1[k4];
        float4 v2 = x2[k4];
        float4 v3 = x3[k4];
        a0 += v0.x * w0 + v0.y * w1 + v0.z * w2 + v0.w * w3;
        a1 += v1.x * w0 + v1.y * w1 + v1.z * w2 + v1.w * w3;
        a2 += v2.x * w0 + v2.y * w1 + v2.z * w2 + v2.w * w3;
        a3 += v3.x * w0 + v3.y * w1 + v3.z * w2 + v3.w * w3;
    }

    float b = bhw[c];
    int r0 = row0 + g * 4;
    if (r0     < n) hw[(size_t)(r0    ) * OUT + c] = a0 + b;
    if (r0 + 1 < n) hw[(size_t)(r0 + 1) * OUT + c] = a1 + b;
    if (r0 + 2 < n) hw[(size_t)(r0 + 2) * OUT + c] = a2 + b;
    if (r0 + 3 < n) hw[(size_t)(r0 + 3) * OUT + c] = a3 + b;
}

// ---------------------------------------------------------------------------
// Gather: half-wave per node, lane = feature. Register accumulate, one write.
// out[i][c] = gcn_b[c] + dinv[i]^2*hw[i][c] + sum_edges norm*hw[src][c]
// ---------------------------------------------------------------------------
__global__ __launch_bounds__(256) void gather_nodes(
    const int2* __restrict__ edata,
    const int* __restrict__ off, const int* __restrict__ cnt,
    const float* __restrict__ dinv, const float* __restrict__ hw,
    const float* __restrict__ gcn_b, float* __restrict__ out, int n)
{
    int gid = blockIdx.x * 256 + threadIdx.x;
    int node = gid >> 5;
    int c    = gid & 31;
    if (node >= n) return;

    float di  = dinv[node];
    float acc = di * di * hw[(size_t)node * OUT + c];   // self loop
    int beg = off[node];
    int num = cnt[node];

    int j = 0;
    for (; j + 1 < num; j += 2) {
        int2 e0 = edata[beg + j];
        int2 e1 = edata[beg + j + 1];
        float h0 = hw[(size_t)e0.x * OUT + c];
        float h1 = hw[(size_t)e1.x * OUT + c];
        acc += __int_as_float(e0.y) * h0;
        acc += __int_as_float(e1.y) * h1;
    }
    if (j < num) {
        int2 e0 = edata[beg + j];
        acc += __int_as_float(e0.y) * hw[(size_t)e0.x * OUT + c];
    }
    out[(size_t)node * OUT + c] = acc + gcn_b[c];
}

// ---------------------------------------------------------------------------
extern "C" void kernel_launch(void* const* d_in, const int* in_sizes, int n_in,
                              void* d_out, int out_size, void* d_ws, size_t ws_size,
                              hipStream_t stream)
{
    const float* x      = (const float*)d_in[0];
    const int*   eidx   = (const int*)d_in[1];
    const float* fc1_w  = (const float*)d_in[2];
    const float* fc1_b  = (const float*)d_in[3];
    const float* gcn_w  = (const float*)d_in[4];
    const float* gcn_b  = (const float*)d_in[5];
    float* out = (float*)d_out;

    int n = in_sizes[0] / IN_FEAT;
    int E = in_sizes[1] / 2;
    const int* src = eidx;
    const int* dst = eidx + E;

    int nb = (n + 1023) / 1024;   // scan blocks

    // Workspace layout (4-byte elements, 16B-aligned segments)
    auto align4 = [](size_t v) { return (v + 3) & ~(size_t)3; };
    float* ws = (float*)d_ws;
    size_t o = 0;
    float* W    = ws + o; o = align4(o + (size_t)IN_FEAT * OUT);
    float* bhw  = ws + o; o = align4(o + OUT);
    float* dinv = ws + o; o = align4(o + n);
    int*   cnt  = (int*)(ws + o); o = align4(o + n);
    int*   off  = (int*)(ws + o); o = align4(o + n);
    int*   cur  = (int*)(ws + o); o = align4(o + n);
    int*   bsum = (int*)(ws + o); o = align4(o + nb + 16);
    int2*  edata = (int2*)(ws + o); o = align4(o + (size_t)2 * E);
    float* hw   = ws + o; o = align4(o + (size_t)n * OUT);
    (void)ws_size;

    dim3 blk(256);
    prep_W<<<dim3((IN_FEAT * OUT) / 256), blk, 0, stream>>>(fc1_w, fc1_b, gcn_w, W, bhw);
    zero_cnt<<<dim3((n + 255) / 256), blk, 0, stream>>>(cnt, n);
    count_deg<<<dim3((E + 255) / 256), blk, 0, stream>>>(dst, cnt, E);
    scan1<<<dim3(nb), blk, 0, stream>>>(cnt, bsum, n);
    scan2<<<dim3(1), dim3(64), 0, stream>>>(bsum, nb);
    scan3<<<dim3(nb), blk, 0, stream>>>(cnt, bsum, off, cur, dinv, n);
    permute_edges<<<dim3((E + 255) / 256), blk, 0, stream>>>(src, dst, off, cur, dinv, edata, E);
    gemm_hw2<<<dim3((n + 31) / 32), blk, 0, stream>>>(x, W, bhw, hw, n);
    long long total = (long long)n * OUT;
    gather_nodes<<<dim3((int)((total + 255) / 256)), blk, 0, stream>>>(
        edata, off, cnt, dinv, hw, gcn_b, out, n);
}